// Round 1
// baseline (592.815 us; speedup 1.0000x reference)
//
#include <hip/hip_runtime.h>

#define N_NODES 100000
#define N_EDGES 1600000
#define DIM 64

// Kernel 1: per node n: Xs[n] = x[n] @ W_msg[0:64], XtB[n] = x[n] @ W_msg[64:128] + b_msg.
// Also zeroes agg and cnt (ws is poisoned 0xAA and never re-poisoned between replays).
__global__ __launch_bounds__(256) void node_transform(
    const float* __restrict__ x, const float* __restrict__ W_msg,
    const float* __restrict__ b_msg,
    float* __restrict__ Xs, float* __restrict__ XtB,
    float* __restrict__ agg, float* __restrict__ cnt)
{
    __shared__ float Ws[DIM][DIM];   // W_msg rows 0..63, [k][j]
    __shared__ float Wt[DIM][DIM];   // W_msg rows 64..127
    __shared__ float xrow[4][DIM];

    for (int i = threadIdx.x; i < DIM * DIM; i += 256) {
        Ws[i >> 6][i & 63] = W_msg[i];
        Wt[i >> 6][i & 63] = W_msg[DIM * DIM + i];
    }
    __syncthreads();

    const int lane = threadIdx.x & 63;
    const int sub  = threadIdx.x >> 6;          // 0..3 (one wave each)
    const float bj = b_msg[lane];
    const int base = blockIdx.x * 64;           // 64 nodes per block

    for (int it = 0; it < 16; ++it) {
        const int n = base + it * 4 + sub;
        __syncthreads();
        if (n < N_NODES) xrow[sub][lane] = x[n * DIM + lane];
        __syncthreads();
        if (n < N_NODES) {
            float a0 = 0.f, a1 = 0.f;
            #pragma unroll
            for (int k = 0; k < DIM; ++k) {
                const float xv = xrow[sub][k];   // same-address broadcast: free
                a0 += xv * Ws[k][lane];          // consecutive lanes: 2-way alias, free
                a1 += xv * Wt[k][lane];
            }
            Xs [n * DIM + lane] = a0;
            XtB[n * DIM + lane] = a1 + bj;
            agg[n * DIM + lane] = 0.f;
            if (lane == 0) cnt[n] = 0.f;
        }
    }
}

// Kernel 2: per edge e (64 lanes): m = relu(Xs[src] + XtB[tgt]); atomic scatter to agg[tgt].
__global__ __launch_bounds__(256) void edge_scatter(
    const int* __restrict__ eidx,
    const float* __restrict__ Xs, const float* __restrict__ XtB,
    float* __restrict__ agg, float* __restrict__ cnt)
{
    const int e    = blockIdx.x * 4 + (threadIdx.x >> 6);
    const int lane = threadIdx.x & 63;
    if (e >= N_EDGES) return;
    const int s = eidx[e];
    const int t = eidx[N_EDGES + e];
    float m = Xs[s * DIM + lane] + XtB[t * DIM + lane];
    m = fmaxf(m, 0.f);
    atomicAdd(&agg[t * DIM + lane], m);
    if (lane == 0) atomicAdd(&cnt[t], 1.0f);
}

// Kernel 3: out[n] = relu(x[n] @ W_upd[0:64] + (agg[n]/max(cnt,1)) @ W_upd[64:128] + b_upd)
__global__ __launch_bounds__(256) void node_update(
    const float* __restrict__ x, const float* __restrict__ agg,
    const float* __restrict__ cnt, const float* __restrict__ W_upd,
    const float* __restrict__ b_upd, float* __restrict__ out)
{
    __shared__ float Wx[DIM][DIM];
    __shared__ float Wa[DIM][DIM];
    __shared__ float xrow[4][DIM];
    __shared__ float arow[4][DIM];

    for (int i = threadIdx.x; i < DIM * DIM; i += 256) {
        Wx[i >> 6][i & 63] = W_upd[i];
        Wa[i >> 6][i & 63] = W_upd[DIM * DIM + i];
    }
    __syncthreads();

    const int lane = threadIdx.x & 63;
    const int sub  = threadIdx.x >> 6;
    const float bj = b_upd[lane];
    const int base = blockIdx.x * 64;

    for (int it = 0; it < 16; ++it) {
        const int n = base + it * 4 + sub;
        __syncthreads();
        if (n < N_NODES) {
            const float inv = 1.0f / fmaxf(cnt[n], 1.0f);
            xrow[sub][lane] = x[n * DIM + lane];
            arow[sub][lane] = agg[n * DIM + lane] * inv;
        }
        __syncthreads();
        if (n < N_NODES) {
            float a = bj;
            #pragma unroll
            for (int k = 0; k < DIM; ++k) {
                a += xrow[sub][k] * Wx[k][lane];
                a += arow[sub][k] * Wa[k][lane];
            }
            out[n * DIM + lane] = fmaxf(a, 0.f);
        }
    }
}

extern "C" void kernel_launch(void* const* d_in, const int* in_sizes, int n_in,
                              void* d_out, int out_size, void* d_ws, size_t ws_size,
                              hipStream_t stream) {
    const float* x     = (const float*)d_in[0];
    const int*   eidx  = (const int*)  d_in[1];   // [2][E] int32
    const float* W_msg = (const float*)d_in[2];   // [128][64]
    const float* b_msg = (const float*)d_in[3];   // [64]
    const float* W_upd = (const float*)d_in[4];   // [128][64]
    const float* b_upd = (const float*)d_in[5];   // [64]
    float* out = (float*)d_out;

    float* Xs  = (float*)d_ws;                 // [N][64]
    float* XtB = Xs  + (size_t)N_NODES * DIM;  // [N][64]
    float* agg = XtB + (size_t)N_NODES * DIM;  // [N][64]
    float* cnt = agg + (size_t)N_NODES * DIM;  // [N]

    const int nodeBlocks = (N_NODES + 63) / 64;   // 1563
    node_transform<<<nodeBlocks, 256, 0, stream>>>(x, W_msg, b_msg, Xs, XtB, agg, cnt);
    edge_scatter<<<(N_EDGES + 3) / 4, 256, 0, stream>>>(eidx, Xs, XtB, agg, cnt);
    node_update<<<nodeBlocks, 256, 0, stream>>>(x, agg, cnt, W_upd, b_upd, out);
}

// Round 2
// 574.732 us; speedup vs baseline: 1.0315x; 1.0315x over previous
//
#include <hip/hip_runtime.h>
#include <hip/hip_bf16.h>

#define N_NODES 100000
#define N_EDGES 1600000
#define DIM 64

__device__ __forceinline__ float b2f(unsigned short u) {
    return __uint_as_float(((unsigned int)u) << 16);
}
__device__ __forceinline__ unsigned short f2b(float f) {
    __hip_bfloat16 h = __float2bfloat16(f);
    return *reinterpret_cast<unsigned short*>(&h);
}

// K1: per node n: XsB[n] = bf16(x[n] @ W_msg[0:64]), XtB[n] = bf16(x[n] @ W_msg[64:128] + b_msg)
// Each thread computes 4 nodes (same out-column) -> W LDS read amortized 4x.
// Also zeroes deg[] (ws is poisoned 0xAA; must re-init every call).
__global__ __launch_bounds__(256) void node_transform(
    const float* __restrict__ x, const float* __restrict__ W_msg,
    const float* __restrict__ b_msg,
    unsigned short* __restrict__ XsB, unsigned short* __restrict__ XtB,
    int* __restrict__ deg)
{
    __shared__ float Ws[DIM][DIM];
    __shared__ float Wt[DIM][DIM];
    __shared__ float xt[16][DIM];

    const int tid = threadIdx.x;
    const int gtid = blockIdx.x * 256 + tid;     // grid 1563*256 = 400128 >= N
    if (gtid < N_NODES) deg[gtid] = 0;

    for (int i = tid; i < DIM * DIM; i += 256) {
        Ws[i >> 6][i & 63] = W_msg[i];
        Wt[i >> 6][i & 63] = W_msg[DIM * DIM + i];
    }
    const int lane = tid & 63, w = tid >> 6;
    const float bj = b_msg[lane];
    const int base0 = blockIdx.x * 64;

    for (int it = 0; it < 4; ++it) {
        const int nb = base0 + it * 16;          // 16 nodes this iter
        __syncthreads();
        for (int i = tid; i < 16 * DIM; i += 256) {
            const int nn = nb + (i >> 6);
            xt[i >> 6][i & 63] = (nn < N_NODES) ? x[nn * DIM + (i & 63)] : 0.f;
        }
        __syncthreads();
        float as[4] = {0.f, 0.f, 0.f, 0.f};
        float at[4] = {0.f, 0.f, 0.f, 0.f};
        #pragma unroll
        for (int k = 0; k < DIM; ++k) {
            const float ws = Ws[k][lane];        // lanes 0..63 stride-1: conflict-free
            const float wt = Wt[k][lane];
            #pragma unroll
            for (int m = 0; m < 4; ++m) {
                const float xv = xt[w * 4 + m][k];  // same-addr broadcast: free
                as[m] += xv * ws;
                at[m] += xv * wt;
            }
        }
        #pragma unroll
        for (int m = 0; m < 4; ++m) {
            const int n = nb + w * 4 + m;
            if (n < N_NODES) {
                XsB[n * DIM + lane] = f2b(as[m]);
                XtB[n * DIM + lane] = f2b(at[m] + bj);
            }
        }
    }
}

// K2a: degree histogram over targets
__global__ __launch_bounds__(256) void hist(const int* __restrict__ eidx,
                                            int* __restrict__ deg)
{
    const int e = blockIdx.x * 256 + threadIdx.x;
    if (e < N_EDGES) atomicAdd(&deg[eidx[N_EDGES + e]], 1);
}

// K2b: per-block exclusive scan of deg -> row; block totals -> bsum
__global__ __launch_bounds__(1024) void scan_blocks(const int* __restrict__ deg,
                                                    int* __restrict__ row,
                                                    int* __restrict__ bsum)
{
    __shared__ int wsum[16];
    const int i = blockIdx.x * 1024 + threadIdx.x;
    const int lane = threadIdx.x & 63, wid = threadIdx.x >> 6;
    const int v = (i < N_NODES) ? deg[i] : 0;
    int s = v;
    #pragma unroll
    for (int d = 1; d < 64; d <<= 1) {
        int u = __shfl_up(s, d);
        if (lane >= d) s += u;
    }
    if (lane == 63) wsum[wid] = s;
    __syncthreads();
    if (wid == 0) {
        int ws = (lane < 16) ? wsum[lane] : 0;
        #pragma unroll
        for (int d = 1; d < 16; d <<= 1) {
            int u = __shfl_up(ws, d);
            if (lane >= d) ws += u;
        }
        if (lane < 16) wsum[lane] = ws;
    }
    __syncthreads();
    const int base = wid ? wsum[wid - 1] : 0;
    if (i < N_NODES) row[i] = base + s - v;      // block-local exclusive
    if (threadIdx.x == 1023) bsum[blockIdx.x] = wsum[15];
}

// K2c: exclusive scan of the 98 block sums (single 128-thread block)
__global__ __launch_bounds__(128) void scan_partials(int* __restrict__ bsum, int nb)
{
    __shared__ int wsum[2];
    const int i = threadIdx.x;
    const int lane = i & 63, wid = i >> 6;
    const int v = (i < nb) ? bsum[i] : 0;
    int s = v;
    #pragma unroll
    for (int d = 1; d < 64; d <<= 1) {
        int u = __shfl_up(s, d);
        if (lane >= d) s += u;
    }
    if (lane == 63) wsum[wid] = s;
    __syncthreads();
    const int base = wid ? wsum[0] : 0;
    if (i < nb) bsum[i] = base + s - v;          // exclusive
}

// K2d: add block base; init cursor = row_start
__global__ __launch_bounds__(1024) void add_base(int* __restrict__ row,
                                                 const int* __restrict__ bsum,
                                                 int* __restrict__ cursor)
{
    const int i = blockIdx.x * 1024 + threadIdx.x;
    if (i < N_NODES) {
        const int r = row[i] + bsum[blockIdx.x];
        row[i] = r;
        cursor[i] = r;
    }
}

// K2e: fill CSR source-index array
__global__ __launch_bounds__(256) void fill_csr(const int* __restrict__ eidx,
                                                int* __restrict__ cursor,
                                                int* __restrict__ csr)
{
    const int e = blockIdx.x * 256 + threadIdx.x;
    if (e < N_EDGES) {
        const int t = eidx[N_EDGES + e];
        const int pos = atomicAdd(&cursor[t], 1);
        csr[pos] = eidx[e];
    }
}

// K3: per node (one wave): agg[n] = mean_e relu(XsB[src(e)] + XtB[n]) — no atomics.
__global__ __launch_bounds__(256) void aggregate(
    const int* __restrict__ row, const int* __restrict__ deg,
    const int* __restrict__ csr,
    const unsigned short* __restrict__ XsB, const unsigned short* __restrict__ XtB,
    float* __restrict__ agg)
{
    const int n = blockIdx.x * 4 + (threadIdx.x >> 6);
    const int lane = threadIdx.x & 63;
    if (n >= N_NODES) return;
    const int start = row[n];
    const int d = deg[n];
    const float xtb = b2f(XtB[n * DIM + lane]);
    float acc = 0.f;
    int i = 0;
    for (; i + 4 <= d; i += 4) {                 // 4 independent gathers in flight
        const int s0 = csr[start + i];
        const int s1 = csr[start + i + 1];
        const int s2 = csr[start + i + 2];
        const int s3 = csr[start + i + 3];
        const float m0 = b2f(XsB[s0 * DIM + lane]) + xtb;
        const float m1 = b2f(XsB[s1 * DIM + lane]) + xtb;
        const float m2 = b2f(XsB[s2 * DIM + lane]) + xtb;
        const float m3 = b2f(XsB[s3 * DIM + lane]) + xtb;
        acc += fmaxf(m0, 0.f) + fmaxf(m1, 0.f) + fmaxf(m2, 0.f) + fmaxf(m3, 0.f);
    }
    for (; i < d; ++i)
        acc += fmaxf(b2f(XsB[csr[start + i] * DIM + lane]) + xtb, 0.f);
    agg[n * DIM + lane] = acc / fmaxf((float)d, 1.f);
}

// K4: out[n] = relu(x[n] @ W_upd[0:64] + agg[n] @ W_upd[64:128] + b_upd), 4 nodes/thread
__global__ __launch_bounds__(256) void node_update(
    const float* __restrict__ x, const float* __restrict__ agg,
    const float* __restrict__ W_upd, const float* __restrict__ b_upd,
    float* __restrict__ out)
{
    __shared__ float Wx[DIM][DIM];
    __shared__ float Wa[DIM][DIM];
    __shared__ float xt[16][DIM];
    __shared__ float at_[16][DIM];

    const int tid = threadIdx.x;
    for (int i = tid; i < DIM * DIM; i += 256) {
        Wx[i >> 6][i & 63] = W_upd[i];
        Wa[i >> 6][i & 63] = W_upd[DIM * DIM + i];
    }
    const int lane = tid & 63, w = tid >> 6;
    const float bj = b_upd[lane];
    const int base0 = blockIdx.x * 64;

    for (int it = 0; it < 4; ++it) {
        const int nb = base0 + it * 16;
        __syncthreads();
        for (int i = tid; i < 16 * DIM; i += 256) {
            const int nn = nb + (i >> 6);
            float xv = 0.f, av = 0.f;
            if (nn < N_NODES) {
                xv = x[nn * DIM + (i & 63)];
                av = agg[nn * DIM + (i & 63)];
            }
            xt[i >> 6][i & 63] = xv;
            at_[i >> 6][i & 63] = av;
        }
        __syncthreads();
        float acc[4] = {bj, bj, bj, bj};
        #pragma unroll
        for (int k = 0; k < DIM; ++k) {
            const float wx = Wx[k][lane];
            const float wa = Wa[k][lane];
            #pragma unroll
            for (int m = 0; m < 4; ++m) {
                acc[m] += xt[w * 4 + m][k] * wx + at_[w * 4 + m][k] * wa;
            }
        }
        #pragma unroll
        for (int m = 0; m < 4; ++m) {
            const int n = nb + w * 4 + m;
            if (n < N_NODES) out[n * DIM + lane] = fmaxf(acc[m], 0.f);
        }
    }
}

extern "C" void kernel_launch(void* const* d_in, const int* in_sizes, int n_in,
                              void* d_out, int out_size, void* d_ws, size_t ws_size,
                              hipStream_t stream) {
    const float* x     = (const float*)d_in[0];
    const int*   eidx  = (const int*)  d_in[1];   // [2][E] int32
    const float* W_msg = (const float*)d_in[2];   // [128][64]
    const float* b_msg = (const float*)d_in[3];   // [64]
    const float* W_upd = (const float*)d_in[4];   // [128][64]
    const float* b_upd = (const float*)d_in[5];   // [64]
    float* out = (float*)d_out;

    // workspace layout (floats/ints first for alignment)
    float* agg    = (float*)d_ws;                          // [N][64]  25.6 MB
    int*   deg    = (int*)(agg + (size_t)N_NODES * DIM);   // [N]
    int*   row    = deg + N_NODES;                         // [N]
    int*   cursor = row + N_NODES;                         // [N]
    int*   bsum   = cursor + N_NODES;                      // [128]
    int*   csr    = bsum + 128;                            // [E]      6.4 MB
    unsigned short* XsB = (unsigned short*)(csr + N_EDGES);// [N][64]  12.8 MB
    unsigned short* XtB = XsB + (size_t)N_NODES * DIM;     // [N][64]  12.8 MB

    const int nodeBlocks = (N_NODES + 63) / 64;    // 1563
    const int edgeBlocks = (N_EDGES + 255) / 256;  // 6250
    const int scanBlocks = (N_NODES + 1023) / 1024; // 98

    node_transform<<<nodeBlocks, 256, 0, stream>>>(x, W_msg, b_msg, XsB, XtB, deg);
    hist<<<edgeBlocks, 256, 0, stream>>>(eidx, deg);
    scan_blocks<<<scanBlocks, 1024, 0, stream>>>(deg, row, bsum);
    scan_partials<<<1, 128, 0, stream>>>(bsum, scanBlocks);
    add_base<<<scanBlocks, 1024, 0, stream>>>(row, bsum, cursor);
    fill_csr<<<edgeBlocks, 256, 0, stream>>>(eidx, cursor, csr);
    aggregate<<<(N_NODES + 3) / 4, 256, 0, stream>>>(row, deg, csr, XsB, XtB, agg);
    node_update<<<nodeBlocks, 256, 0, stream>>>(x, agg, W_upd, b_upd, out);
}

// Round 3
// 304.169 us; speedup vs baseline: 1.9490x; 1.8895x over previous
//
#include <hip/hip_runtime.h>
#include <hip/hip_bf16.h>

#define N_NODES 100000
#define N_EDGES 1600000
#define DIM 64

typedef __attribute__((ext_vector_type(8))) short bf16x8;
typedef __attribute__((ext_vector_type(4))) float f32x4;

__device__ __forceinline__ float b2f(unsigned int u16) {
    return __uint_as_float(u16 << 16);
}
__device__ __forceinline__ unsigned short f2bs(float f) {
    __hip_bfloat16 h = __float2bfloat16(f);
    return *reinterpret_cast<unsigned short*>(&h);
}

// K1 (MFMA): XsB = bf16(x @ Wm[0:64]), XtB = bf16(x @ Wm[64:128] + b), xB = bf16(x).
// Block = 64 rows (4 waves x 16 rows), out-cols 0..127 as 8 col-tiles, K=64 (2 MFMA steps).
// Fragment k-mapping: k = kk*32 + (lane>>4)*8 + j  (same bijection for A and B => valid).
// Also zeroes deg[] (ws is poisoned; must re-init every call).
__global__ __launch_bounds__(256) void node_transform(
    const float* __restrict__ x, const float* __restrict__ W_msg,
    const float* __restrict__ b_msg,
    unsigned short* __restrict__ XsB, unsigned short* __restrict__ XtB,
    unsigned short* __restrict__ xB, int* __restrict__ deg)
{
    __shared__ unsigned short WB[8192];   // [ct(8)][kk(2)][lane(64)][j(8)]
    const int tid = threadIdx.x;
    const int gtid = blockIdx.x * 256 + tid;
    if (gtid < N_NODES) deg[gtid] = 0;

    for (int i = tid; i < 8192; i += 256) {
        const int j = i & 7, l = (i >> 3) & 63, kk = (i >> 9) & 1, ct = i >> 10;
        const int k = kk * 32 + ((l >> 4) << 3) + j;     // [0,64)
        const int c = ct * 16 + (l & 15);                // [0,128)
        // B'[k][c] = W_msg[(c>=64)*64 + k][c&63]
        WB[i] = f2bs(W_msg[(((c >> 6) << 6) + k) * 64 + (c & 63)]);
    }
    __syncthreads();

    const int lane = tid & 63, w = tid >> 6;
    const int r0 = blockIdx.x * 64 + w * 16;
    if (r0 >= N_NODES) return;                            // whole-wave guard (N%16==0)

    f32x4 acc[8];
    #pragma unroll
    for (int ct = 0; ct < 8; ++ct) acc[ct] = (f32x4){0.f, 0.f, 0.f, 0.f};

    const int r = r0 + (lane & 15);
    #pragma unroll
    for (int kk = 0; kk < 2; ++kk) {
        const int off = kk * 32 + ((lane >> 4) << 3);
        const float4* xp = reinterpret_cast<const float4*>(&x[r * 64 + off]);
        const float4 p0 = xp[0], p1 = xp[1];
        bf16x8 a;
        a[0] = (short)f2bs(p0.x); a[1] = (short)f2bs(p0.y);
        a[2] = (short)f2bs(p0.z); a[3] = (short)f2bs(p0.w);
        a[4] = (short)f2bs(p1.x); a[5] = (short)f2bs(p1.y);
        a[6] = (short)f2bs(p1.z); a[7] = (short)f2bs(p1.w);
        *reinterpret_cast<bf16x8*>(&xB[r * 64 + off]) = a;   // bf16 copy of x for K4
        #pragma unroll
        for (int ct = 0; ct < 8; ++ct) {
            const bf16x8 b = *reinterpret_cast<const bf16x8*>(
                &WB[(((ct << 1) | kk) * 64 + lane) << 3]);
            acc[ct] = __builtin_amdgcn_mfma_f32_16x16x32_bf16(a, b, acc[ct], 0, 0, 0);
        }
    }

    // C/D: col = lane&15, row = (lane>>4)*4 + q   [m89-verified]
    const int rb = r0 + ((lane >> 4) << 2);
    #pragma unroll
    for (int ct = 0; ct < 8; ++ct) {
        const int c = ct * 16 + (lane & 15);
        if (c < 64) {
            #pragma unroll
            for (int q = 0; q < 4; ++q)
                XsB[(rb + q) * 64 + c] = f2bs(acc[ct][q]);
        } else {
            const float bj = b_msg[c - 64];
            #pragma unroll
            for (int q = 0; q < 4; ++q)
                XtB[(rb + q) * 64 + (c - 64)] = f2bs(acc[ct][q] + bj);
        }
    }
}

// K2a: degree histogram over targets
__global__ __launch_bounds__(256) void hist(const int* __restrict__ eidx,
                                            int* __restrict__ deg)
{
    const int e = blockIdx.x * 256 + threadIdx.x;
    if (e < N_EDGES) atomicAdd(&deg[eidx[N_EDGES + e]], 1);
}

// K2b: per-block exclusive scan of deg -> row; block totals -> bsum
__global__ __launch_bounds__(1024) void scan_blocks(const int* __restrict__ deg,
                                                    int* __restrict__ row,
                                                    int* __restrict__ bsum)
{
    __shared__ int wsum[16];
    const int i = blockIdx.x * 1024 + threadIdx.x;
    const int lane = threadIdx.x & 63, wid = threadIdx.x >> 6;
    const int v = (i < N_NODES) ? deg[i] : 0;
    int s = v;
    #pragma unroll
    for (int d = 1; d < 64; d <<= 1) {
        int u = __shfl_up(s, d);
        if (lane >= d) s += u;
    }
    if (lane == 63) wsum[wid] = s;
    __syncthreads();
    if (wid == 0) {
        int ws = (lane < 16) ? wsum[lane] : 0;
        #pragma unroll
        for (int d = 1; d < 16; d <<= 1) {
            int u = __shfl_up(ws, d);
            if (lane >= d) ws += u;
        }
        if (lane < 16) wsum[lane] = ws;
    }
    __syncthreads();
    const int base = wid ? wsum[wid - 1] : 0;
    if (i < N_NODES) row[i] = base + s - v;
    if (threadIdx.x == 1023) bsum[blockIdx.x] = wsum[15];
}

// K2c: exclusive scan of the 98 block sums
__global__ __launch_bounds__(128) void scan_partials(int* __restrict__ bsum, int nb)
{
    __shared__ int wsum[2];
    const int i = threadIdx.x;
    const int lane = i & 63, wid = i >> 6;
    const int v = (i < nb) ? bsum[i] : 0;
    int s = v;
    #pragma unroll
    for (int d = 1; d < 64; d <<= 1) {
        int u = __shfl_up(s, d);
        if (lane >= d) s += u;
    }
    if (lane == 63) wsum[wid] = s;
    __syncthreads();
    const int base = wid ? wsum[0] : 0;
    if (i < nb) bsum[i] = base + s - v;
}

// K2d: add block base; init cursor
__global__ __launch_bounds__(1024) void add_base(int* __restrict__ row,
                                                 const int* __restrict__ bsum,
                                                 int* __restrict__ cursor)
{
    const int i = blockIdx.x * 1024 + threadIdx.x;
    if (i < N_NODES) {
        const int r = row[i] + bsum[blockIdx.x];
        row[i] = r;
        cursor[i] = r;
    }
}

// K2e: fill CSR source-index array
__global__ __launch_bounds__(256) void fill_csr(const int* __restrict__ eidx,
                                                int* __restrict__ cursor,
                                                int* __restrict__ csr)
{
    const int e = blockIdx.x * 256 + threadIdx.x;
    if (e < N_EDGES) {
        const int t = eidx[N_EDGES + e];
        const int pos = atomicAdd(&cursor[t], 1);
        csr[pos] = eidx[e];
    }
}

// K3: wave per node; half-waves gather 2 edges each per iter as uint (2 bf16) per lane.
// aggB = bf16(mean_e relu(Xs[src] + Xt[n])) — no atomics.
__global__ __launch_bounds__(256) void aggregate(
    const int* __restrict__ row, const int* __restrict__ deg,
    const int* __restrict__ csr,
    const unsigned int* __restrict__ Xs32, const unsigned int* __restrict__ Xt32,
    unsigned int* __restrict__ agg32)
{
    const int n = blockIdx.x * 4 + (threadIdx.x >> 6);
    const int lane = threadIdx.x & 63;
    if (n >= N_NODES) return;
    const int c = lane & 31;              // uint column (covers bf16 cols 2c, 2c+1)
    const int h = lane >> 5;              // half-wave id
    const int start = row[n], d = deg[n];
    const unsigned int xt = Xt32[n * 32 + c];
    const float t0 = b2f(xt & 0xffffu), t1 = b2f(xt >> 16);
    float a0 = 0.f, a1 = 0.f;
    int i = 0;
    for (; i + 4 <= d; i += 4) {          // 4 edges/iter: 2 per half-wave, 2 in flight
        const int sA = csr[start + i + h];
        const int sB = csr[start + i + 2 + h];
        const unsigned int uA = Xs32[sA * 32 + c];
        const unsigned int uB = Xs32[sB * 32 + c];
        a0 += fmaxf(b2f(uA & 0xffffu) + t0, 0.f) + fmaxf(b2f(uB & 0xffffu) + t0, 0.f);
        a1 += fmaxf(b2f(uA >> 16) + t1, 0.f) + fmaxf(b2f(uB >> 16) + t1, 0.f);
    }
    if (h == 0) {
        for (; i < d; ++i) {
            const int s = csr[start + i];
            const unsigned int u = Xs32[s * 32 + c];
            a0 += fmaxf(b2f(u & 0xffffu) + t0, 0.f);
            a1 += fmaxf(b2f(u >> 16) + t1, 0.f);
        }
    }
    a0 += __shfl_xor(a0, 32);
    a1 += __shfl_xor(a1, 32);
    if (h == 0) {
        const float inv = (d > 0) ? 1.0f / (float)d : 0.f;
        agg32[n * 32 + c] = (unsigned int)f2bs(a0 * inv) |
                            ((unsigned int)f2bs(a1 * inv) << 16);
    }
}

// K4 (MFMA): out = relu([xB | aggB] @ W_upd + b_upd). K=128 (4 steps), 4 col-tiles.
__global__ __launch_bounds__(256) void node_update(
    const unsigned short* __restrict__ xB, const unsigned short* __restrict__ aggB,
    const float* __restrict__ W_upd, const float* __restrict__ b_upd,
    float* __restrict__ out)
{
    __shared__ unsigned short WB[8192];   // [ct(4)][kk(4)][lane(64)][j(8)]
    const int tid = threadIdx.x;
    for (int i = tid; i < 8192; i += 256) {
        const int j = i & 7, l = (i >> 3) & 63, kk = (i >> 9) & 3, ct = i >> 11;
        const int k = kk * 32 + ((l >> 4) << 3) + j;     // [0,128)
        const int c = ct * 16 + (l & 15);                // [0,64)
        WB[i] = f2bs(W_upd[k * 64 + c]);
    }
    __syncthreads();

    const int lane = tid & 63, w = tid >> 6;
    const int r0 = blockIdx.x * 64 + w * 16;
    if (r0 >= N_NODES) return;

    f32x4 acc[4];
    #pragma unroll
    for (int ct = 0; ct < 4; ++ct) acc[ct] = (f32x4){0.f, 0.f, 0.f, 0.f};

    const int r = r0 + (lane & 15);
    #pragma unroll
    for (int kk = 0; kk < 4; ++kk) {
        const int off = kk * 32 + ((lane >> 4) << 3);     // [0,128)
        const unsigned short* src = (off < 64) ? &xB[r * 64 + off]
                                               : &aggB[r * 64 + off - 64];
        const bf16x8 a = *reinterpret_cast<const bf16x8*>(src);
        #pragma unroll
        for (int ct = 0; ct < 4; ++ct) {
            const bf16x8 b = *reinterpret_cast<const bf16x8*>(
                &WB[(((ct << 2) | kk) * 64 + lane) << 3]);
            acc[ct] = __builtin_amdgcn_mfma_f32_16x16x32_bf16(a, b, acc[ct], 0, 0, 0);
        }
    }

    const int rb = r0 + ((lane >> 4) << 2);
    #pragma unroll
    for (int ct = 0; ct < 4; ++ct) {
        const int c = ct * 16 + (lane & 15);
        const float bj = b_upd[c];
        #pragma unroll
        for (int q = 0; q < 4; ++q)
            out[(rb + q) * 64 + c] = fmaxf(acc[ct][q] + bj, 0.f);
    }
}

extern "C" void kernel_launch(void* const* d_in, const int* in_sizes, int n_in,
                              void* d_out, int out_size, void* d_ws, size_t ws_size,
                              hipStream_t stream) {
    const float* x     = (const float*)d_in[0];
    const int*   eidx  = (const int*)  d_in[1];   // [2][E] int32
    const float* W_msg = (const float*)d_in[2];   // [128][64]
    const float* b_msg = (const float*)d_in[3];   // [64]
    const float* W_upd = (const float*)d_in[4];   // [128][64]
    const float* b_upd = (const float*)d_in[5];   // [64]
    float* out = (float*)d_out;

    int* deg    = (int*)d_ws;                      // [N]
    int* row    = deg + N_NODES;                   // [N]
    int* cursor = row + N_NODES;                   // [N]
    int* bsum   = cursor + N_NODES;                // [128]
    int* csr    = bsum + 128;                      // [E]
    unsigned short* XsB  = (unsigned short*)(csr + N_EDGES);  // [N][64] bf16
    unsigned short* XtB  = XsB + (size_t)N_NODES * DIM;       // [N][64] bf16
    unsigned short* xB   = XtB + (size_t)N_NODES * DIM;       // [N][64] bf16
    unsigned short* aggB = xB  + (size_t)N_NODES * DIM;       // [N][64] bf16

    const int nodeBlocks = (N_NODES + 63) / 64;     // 1563
    const int edgeBlocks = (N_EDGES + 255) / 256;   // 6250
    const int scanBlocks = (N_NODES + 1023) / 1024; // 98

    node_transform<<<nodeBlocks, 256, 0, stream>>>(x, W_msg, b_msg, XsB, XtB, xB, deg);
    hist<<<edgeBlocks, 256, 0, stream>>>(eidx, deg);
    scan_blocks<<<scanBlocks, 1024, 0, stream>>>(deg, row, bsum);
    scan_partials<<<1, 128, 0, stream>>>(bsum, scanBlocks);
    add_base<<<scanBlocks, 1024, 0, stream>>>(row, bsum, cursor);
    fill_csr<<<edgeBlocks, 256, 0, stream>>>(eidx, cursor, csr);
    aggregate<<<(N_NODES + 3) / 4, 256, 0, stream>>>(row, deg, csr,
        (const unsigned int*)XsB, (const unsigned int*)XtB, (unsigned int*)aggB);
    node_update<<<nodeBlocks, 256, 0, stream>>>(xB, aggB, W_upd, b_upd, out);
}

// Round 4
// 247.957 us; speedup vs baseline: 2.3908x; 1.2267x over previous
//
#include <hip/hip_runtime.h>
#include <hip/hip_bf16.h>

#define N_NODES 100000
#define N_EDGES 1600000
#define DIM 64

typedef __attribute__((ext_vector_type(8))) short bf16x8;
typedef __attribute__((ext_vector_type(4))) float f32x4;

__device__ __forceinline__ float b2f(unsigned int u16) {
    return __uint_as_float(u16 << 16);
}
__device__ __forceinline__ unsigned short f2bs(float f) {
    __hip_bfloat16 h = __float2bfloat16(f);
    return *reinterpret_cast<unsigned short*>(&h);
}

// K1 (MFMA): XsB = bf16(x @ Wm[0:64]), XtB = bf16(x @ Wm[64:128] + b), xB = bf16(x).
// Block = 64 rows (4 waves x 16 rows), out-cols 0..127 as 8 col-tiles, K=64 (2 MFMA steps).
// Fragment k-mapping: k = kk*32 + (lane>>4)*8 + j  (same bijection for A and B => valid).
// Also zeroes deg[] (ws is poisoned; must re-init every call).
__global__ __launch_bounds__(256) void node_transform(
    const float* __restrict__ x, const float* __restrict__ W_msg,
    const float* __restrict__ b_msg,
    unsigned short* __restrict__ XsB, unsigned short* __restrict__ XtB,
    unsigned short* __restrict__ xB, int* __restrict__ deg)
{
    __shared__ unsigned short WB[8192];   // [ct(8)][kk(2)][lane(64)][j(8)]
    const int tid = threadIdx.x;
    const int gtid = blockIdx.x * 256 + tid;
    if (gtid < N_NODES) deg[gtid] = 0;

    for (int i = tid; i < 8192; i += 256) {
        const int j = i & 7, l = (i >> 3) & 63, kk = (i >> 9) & 1, ct = i >> 10;
        const int k = kk * 32 + ((l >> 4) << 3) + j;     // [0,64)
        const int c = ct * 16 + (l & 15);                // [0,128)
        WB[i] = f2bs(W_msg[(((c >> 6) << 6) + k) * 64 + (c & 63)]);
    }
    __syncthreads();

    const int lane = tid & 63, w = tid >> 6;
    const int r0 = blockIdx.x * 64 + w * 16;
    if (r0 >= N_NODES) return;

    f32x4 acc[8];
    #pragma unroll
    for (int ct = 0; ct < 8; ++ct) acc[ct] = (f32x4){0.f, 0.f, 0.f, 0.f};

    const int r = r0 + (lane & 15);
    #pragma unroll
    for (int kk = 0; kk < 2; ++kk) {
        const int off = kk * 32 + ((lane >> 4) << 3);
        const float4* xp = reinterpret_cast<const float4*>(&x[r * 64 + off]);
        const float4 p0 = xp[0], p1 = xp[1];
        bf16x8 a;
        a[0] = (short)f2bs(p0.x); a[1] = (short)f2bs(p0.y);
        a[2] = (short)f2bs(p0.z); a[3] = (short)f2bs(p0.w);
        a[4] = (short)f2bs(p1.x); a[5] = (short)f2bs(p1.y);
        a[6] = (short)f2bs(p1.z); a[7] = (short)f2bs(p1.w);
        *reinterpret_cast<bf16x8*>(&xB[r * 64 + off]) = a;
        #pragma unroll
        for (int ct = 0; ct < 8; ++ct) {
            const bf16x8 b = *reinterpret_cast<const bf16x8*>(
                &WB[(((ct << 1) | kk) * 64 + lane) << 3]);
            acc[ct] = __builtin_amdgcn_mfma_f32_16x16x32_bf16(a, b, acc[ct], 0, 0, 0);
        }
    }

    const int rb = r0 + ((lane >> 4) << 2);
    #pragma unroll
    for (int ct = 0; ct < 8; ++ct) {
        const int c = ct * 16 + (lane & 15);
        if (c < 64) {
            #pragma unroll
            for (int q = 0; q < 4; ++q)
                XsB[(rb + q) * 64 + c] = f2bs(acc[ct][q]);
        } else {
            const float bj = b_msg[c - 64];
            #pragma unroll
            for (int q = 0; q < 4; ++q)
                XtB[(rb + q) * 64 + (c - 64)] = f2bs(acc[ct][q] + bj);
        }
    }
}

// K2a: degree histogram over targets (int4-vectorized)
__global__ __launch_bounds__(256) void hist(const int* __restrict__ eidx,
                                            int* __restrict__ deg)
{
    const int i = blockIdx.x * 256 + threadIdx.x;       // quad index
    if (i * 4 < N_EDGES) {
        const int4 t4 = reinterpret_cast<const int4*>(eidx + N_EDGES)[i];
        atomicAdd(&deg[t4.x], 1);
        atomicAdd(&deg[t4.y], 1);
        atomicAdd(&deg[t4.z], 1);
        atomicAdd(&deg[t4.w], 1);
    }
}

// K2b: per-block exclusive scan of deg -> row; block totals -> bsum
__global__ __launch_bounds__(1024) void scan_blocks(const int* __restrict__ deg,
                                                    int* __restrict__ row,
                                                    int* __restrict__ bsum)
{
    __shared__ int wsum[16];
    const int i = blockIdx.x * 1024 + threadIdx.x;
    const int lane = threadIdx.x & 63, wid = threadIdx.x >> 6;
    const int v = (i < N_NODES) ? deg[i] : 0;
    int s = v;
    #pragma unroll
    for (int d = 1; d < 64; d <<= 1) {
        int u = __shfl_up(s, d);
        if (lane >= d) s += u;
    }
    if (lane == 63) wsum[wid] = s;
    __syncthreads();
    if (wid == 0) {
        int ws = (lane < 16) ? wsum[lane] : 0;
        #pragma unroll
        for (int d = 1; d < 16; d <<= 1) {
            int u = __shfl_up(ws, d);
            if (lane >= d) ws += u;
        }
        if (lane < 16) wsum[lane] = ws;
    }
    __syncthreads();
    const int base = wid ? wsum[wid - 1] : 0;
    if (i < N_NODES) row[i] = base + s - v;
    if (threadIdx.x == 1023) bsum[blockIdx.x] = wsum[15];
}

// K2c: exclusive scan of the 98 block sums
__global__ __launch_bounds__(128) void scan_partials(int* __restrict__ bsum, int nb)
{
    __shared__ int wsum[2];
    const int i = threadIdx.x;
    const int lane = i & 63, wid = i >> 6;
    const int v = (i < nb) ? bsum[i] : 0;
    int s = v;
    #pragma unroll
    for (int d = 1; d < 64; d <<= 1) {
        int u = __shfl_up(s, d);
        if (lane >= d) s += u;
    }
    if (lane == 63) wsum[wid] = s;
    __syncthreads();
    const int base = wid ? wsum[0] : 0;
    if (i < nb) bsum[i] = base + s - v;
}

// K2d: add block base; init cursor
__global__ __launch_bounds__(1024) void add_base(int* __restrict__ row,
                                                 const int* __restrict__ bsum,
                                                 int* __restrict__ cursor)
{
    const int i = blockIdx.x * 1024 + threadIdx.x;
    if (i < N_NODES) {
        const int r = row[i] + bsum[blockIdx.x];
        row[i] = r;
        cursor[i] = r;
    }
}

// K2e: fill CSR, class-partitioned to kill write amplification.
// Targets split into 4 classes (t/25000). Blocks of class c=blockIdx&3 scan the
// whole edge stream (coalesced int4) and scatter only class-c edges, so each
// class's ~1.6 MB of active csr tail-lines stays resident in the L2s of one
// blockIdx%8 congruence pair of XCDs and accumulates 16 entries per line.
__global__ __launch_bounds__(256) void fill_csr(const int* __restrict__ eidx,
                                                int* __restrict__ cursor,
                                                int* __restrict__ csr)
{
    const int cls = blockIdx.x & 3;
    const int q   = blockIdx.x >> 2;
    const int NQ  = N_EDGES / 4;                     // 400000 quads
    const int4* src4 = reinterpret_cast<const int4*>(eidx);
    const int4* tgt4 = reinterpret_cast<const int4*>(eidx + N_EDGES);
    const int stride = (gridDim.x >> 2) * 256;
    for (int i = q * 256 + threadIdx.x; i < NQ; i += stride) {
        const int4 t4 = tgt4[i];
        const int4 s4 = src4[i];
        if (t4.x / 25000 == cls) { const int p = atomicAdd(&cursor[t4.x], 1); csr[p] = s4.x; }
        if (t4.y / 25000 == cls) { const int p = atomicAdd(&cursor[t4.y], 1); csr[p] = s4.y; }
        if (t4.z / 25000 == cls) { const int p = atomicAdd(&cursor[t4.z], 1); csr[p] = s4.z; }
        if (t4.w / 25000 == cls) { const int p = atomicAdd(&cursor[t4.w], 1); csr[p] = s4.w; }
    }
}

// K3: wave per node; half-waves gather 4 edges each in flight (uint = 2 bf16 cols).
__global__ __launch_bounds__(256) void aggregate(
    const int* __restrict__ row, const int* __restrict__ deg,
    const int* __restrict__ csr,
    const unsigned int* __restrict__ Xs32, const unsigned int* __restrict__ Xt32,
    unsigned int* __restrict__ agg32)
{
    const int n = blockIdx.x * 4 + (threadIdx.x >> 6);
    const int lane = threadIdx.x & 63;
    if (n >= N_NODES) return;
    const int c = lane & 31;
    const int h = lane >> 5;
    const int start = row[n], d = deg[n];
    const unsigned int xt = Xt32[n * 32 + c];
    const float t0 = b2f(xt & 0xffffu), t1 = b2f(xt >> 16);
    float a0 = 0.f, a1 = 0.f;
    int i = 0;
    for (; i + 8 <= d; i += 8) {          // 8 edges/iter: 4 per half-wave in flight
        const int sA = csr[start + i + h];
        const int sB = csr[start + i + 2 + h];
        const int sC = csr[start + i + 4 + h];
        const int sD = csr[start + i + 6 + h];
        const unsigned int uA = Xs32[sA * 32 + c];
        const unsigned int uB = Xs32[sB * 32 + c];
        const unsigned int uC = Xs32[sC * 32 + c];
        const unsigned int uD = Xs32[sD * 32 + c];
        a0 += fmaxf(b2f(uA & 0xffffu) + t0, 0.f) + fmaxf(b2f(uB & 0xffffu) + t0, 0.f)
            + fmaxf(b2f(uC & 0xffffu) + t0, 0.f) + fmaxf(b2f(uD & 0xffffu) + t0, 0.f);
        a1 += fmaxf(b2f(uA >> 16) + t1, 0.f) + fmaxf(b2f(uB >> 16) + t1, 0.f)
            + fmaxf(b2f(uC >> 16) + t1, 0.f) + fmaxf(b2f(uD >> 16) + t1, 0.f);
    }
    for (; i + 2 <= d; i += 2) {
        const int s = csr[start + i + h];
        const unsigned int u = Xs32[s * 32 + c];
        a0 += fmaxf(b2f(u & 0xffffu) + t0, 0.f);
        a1 += fmaxf(b2f(u >> 16) + t1, 0.f);
    }
    if (h == 0 && i < d) {
        const int s = csr[start + i];
        const unsigned int u = Xs32[s * 32 + c];
        a0 += fmaxf(b2f(u & 0xffffu) + t0, 0.f);
        a1 += fmaxf(b2f(u >> 16) + t1, 0.f);
    }
    a0 += __shfl_xor(a0, 32);
    a1 += __shfl_xor(a1, 32);
    if (h == 0) {
        const float inv = (d > 0) ? 1.0f / (float)d : 0.f;
        agg32[n * 32 + c] = (unsigned int)f2bs(a0 * inv) |
                            ((unsigned int)f2bs(a1 * inv) << 16);
    }
}

// K4 (MFMA): out = relu([xB | aggB] @ W_upd + b_upd). K=128 (4 steps), 4 col-tiles.
__global__ __launch_bounds__(256) void node_update(
    const unsigned short* __restrict__ xB, const unsigned short* __restrict__ aggB,
    const float* __restrict__ W_upd, const float* __restrict__ b_upd,
    float* __restrict__ out)
{
    __shared__ unsigned short WB[8192];   // [ct(4)][kk(4)][lane(64)][j(8)]
    const int tid = threadIdx.x;
    for (int i = tid; i < 8192; i += 256) {
        const int j = i & 7, l = (i >> 3) & 63, kk = (i >> 9) & 3, ct = i >> 11;
        const int k = kk * 32 + ((l >> 4) << 3) + j;
        const int c = ct * 16 + (l & 15);
        WB[i] = f2bs(W_upd[k * 64 + c]);
    }
    __syncthreads();

    const int lane = tid & 63, w = tid >> 6;
    const int r0 = blockIdx.x * 64 + w * 16;
    if (r0 >= N_NODES) return;

    f32x4 acc[4];
    #pragma unroll
    for (int ct = 0; ct < 4; ++ct) acc[ct] = (f32x4){0.f, 0.f, 0.f, 0.f};

    const int r = r0 + (lane & 15);
    #pragma unroll
    for (int kk = 0; kk < 4; ++kk) {
        const int off = kk * 32 + ((lane >> 4) << 3);
        const unsigned short* src = (off < 64) ? &xB[r * 64 + off]
                                               : &aggB[r * 64 + off - 64];
        const bf16x8 a = *reinterpret_cast<const bf16x8*>(src);
        #pragma unroll
        for (int ct = 0; ct < 4; ++ct) {
            const bf16x8 b = *reinterpret_cast<const bf16x8*>(
                &WB[(((ct << 2) | kk) * 64 + lane) << 3]);
            acc[ct] = __builtin_amdgcn_mfma_f32_16x16x32_bf16(a, b, acc[ct], 0, 0, 0);
        }
    }

    const int rb = r0 + ((lane >> 4) << 2);
    #pragma unroll
    for (int ct = 0; ct < 4; ++ct) {
        const int c = ct * 16 + (lane & 15);
        const float bj = b_upd[c];
        #pragma unroll
        for (int q = 0; q < 4; ++q)
            out[(rb + q) * 64 + c] = fmaxf(acc[ct][q] + bj, 0.f);
    }
}

extern "C" void kernel_launch(void* const* d_in, const int* in_sizes, int n_in,
                              void* d_out, int out_size, void* d_ws, size_t ws_size,
                              hipStream_t stream) {
    const float* x     = (const float*)d_in[0];
    const int*   eidx  = (const int*)  d_in[1];   // [2][E] int32
    const float* W_msg = (const float*)d_in[2];   // [128][64]
    const float* b_msg = (const float*)d_in[3];   // [64]
    const float* W_upd = (const float*)d_in[4];   // [128][64]
    const float* b_upd = (const float*)d_in[5];   // [64]
    float* out = (float*)d_out;

    int* deg    = (int*)d_ws;                      // [N]
    int* row    = deg + N_NODES;                   // [N]
    int* cursor = row + N_NODES;                   // [N]
    int* bsum   = cursor + N_NODES;                // [128]
    int* csr    = bsum + 128;                      // [E]
    unsigned short* XsB  = (unsigned short*)(csr + N_EDGES);  // [N][64] bf16
    unsigned short* XtB  = XsB + (size_t)N_NODES * DIM;       // [N][64] bf16
    unsigned short* xB   = XtB + (size_t)N_NODES * DIM;       // [N][64] bf16
    unsigned short* aggB = xB  + (size_t)N_NODES * DIM;       // [N][64] bf16

    const int nodeBlocks = (N_NODES + 63) / 64;     // 1563
    const int quadBlocks = (N_EDGES / 4 + 255) / 256; // 1563
    const int scanBlocks = (N_NODES + 1023) / 1024; // 98

    node_transform<<<nodeBlocks, 256, 0, stream>>>(x, W_msg, b_msg, XsB, XtB, xB, deg);
    hist<<<quadBlocks, 256, 0, stream>>>(eidx, deg);
    scan_blocks<<<scanBlocks, 1024, 0, stream>>>(deg, row, bsum);
    scan_partials<<<1, 128, 0, stream>>>(bsum, scanBlocks);
    add_base<<<scanBlocks, 1024, 0, stream>>>(row, bsum, cursor);
    fill_csr<<<1024, 256, 0, stream>>>(eidx, cursor, csr);
    aggregate<<<(N_NODES + 3) / 4, 256, 0, stream>>>(row, deg, csr,
        (const unsigned int*)XsB, (const unsigned int*)XtB, (unsigned int*)aggB);
    node_update<<<nodeBlocks, 256, 0, stream>>>(xB, aggB, W_upd, b_upd, out);
}